// Round 6
// baseline (359.616 us; speedup 1.0000x reference)
//
#include <hip/hip_runtime.h>
#include <hip/hip_bf16.h>
#include <stdint.h>

typedef __attribute__((ext_vector_type(8))) short short8;
typedef __attribute__((ext_vector_type(4))) short short4v;
typedef __attribute__((ext_vector_type(4))) float f32x4;
typedef __attribute__((ext_vector_type(4))) unsigned int uint4v;

#define MFMA16(A, B, C) __builtin_amdgcn_mfma_f32_16x16x32_bf16(A, B, C, 0, 0, 0)

// async global->LDS, 16B/lane: LDS dest = wave-uniform base + lane*16
#define GLDS16(gp, lp) __builtin_amdgcn_global_load_lds(                     \
    (const __attribute__((address_space(1))) unsigned int*)(gp),             \
    (__attribute__((address_space(3))) unsigned int*)(lp), 16, 0, 0)

static constexpr int kS  = 4096;
static constexpr int kD  = 1024;
static constexpr int kH  = 16;
static constexpr int kHD = 64;

__device__ __forceinline__ short bf16_bits(float f) {
    __hip_bfloat16 h = __float2bfloat16(f);
    return *(short*)&h;
}

// packed 2x fp32 -> bf16x2 (v_cvt_pk_bf16_f32)
__device__ __forceinline__ unsigned int pk_bf16(float a, float b) {
    __hip_bfloat162 h = __float22bfloat162_rn(make_float2(a, b));
    return *(unsigned int*)&h;
}

__device__ __forceinline__ short8 cvt8(const float* __restrict__ p) {
    f32x4 a = ((const f32x4*)p)[0];
    f32x4 b = ((const f32x4*)p)[1];
    short8 r;
    r[0] = bf16_bits(a[0]); r[1] = bf16_bits(a[1]);
    r[2] = bf16_bits(a[2]); r[3] = bf16_bits(a[3]);
    r[4] = bf16_bits(b[0]); r[5] = bf16_bits(b[1]);
    r[6] = bf16_bits(b[2]); r[7] = bf16_bits(b[3]);
    return r;
}

// ---- fp8 e4m3fn (fallback tier only) ----
__device__ __forceinline__ unsigned char f32_to_e4m3(float f) {
    unsigned int u = __float_as_uint(f);
    unsigned int s = (u >> 24) & 0x80u;
    unsigned int a = u & 0x7fffffffu;
    if (a < 0x3c800000u) {
        float af = __uint_as_float(a);
        unsigned int sub = (unsigned int)(af * 512.0f + 0.5f);
        return (unsigned char)(s | sub);
    }
    unsigned int r = a + 0x80000u;
    unsigned int m = (r >> 20) & 7u;
    int eb = (int)(r >> 23) - 127 + 7;
    unsigned int bits = ((unsigned int)eb << 3) | m;
    if (bits > 0x7Eu) bits = 0x7Eu;
    return (unsigned char)(s | bits);
}
__device__ __forceinline__ float e4m3_to_f32(unsigned int b) {
    unsigned int s = b & 0x80u;
    unsigned int e = (b >> 3) & 15u;
    unsigned int m = b & 7u;
    float f = e ? __uint_as_float(((e + 120u) << 23) | (m << 20))
                : (float)m * 0.001953125f;
    return s ? -f : f;
}

// fp32 -> bf16, 4/thread; launch with n/1024 blocks.
__global__ __launch_bounds__(256) void cvt_f32_bf16(
    const float* __restrict__ src, __hip_bfloat16* __restrict__ dst)
{
    const int i = blockIdx.x * 256 + threadIdx.x;
    f32x4 v = ((const f32x4*)src)[i];
    short4v o;
    o[0] = bf16_bits(v[0]); o[1] = bf16_bits(v[1]);
    o[2] = bf16_bits(v[2]); o[3] = bf16_bits(v[3]);
    ((short4v*)dst)[i] = o;
}

// 4 weight matrices -> one contiguous bf16 dst (each kD*kD). Grid 4096.
__global__ __launch_bounds__(256) void cvt_w4(
    const float* __restrict__ w0, const float* __restrict__ w1,
    const float* __restrict__ w2, const float* __restrict__ w3,
    __hip_bfloat16* __restrict__ dst)
{
    const int blk = blockIdx.x;
    const int sel = blk >> 10;
    const float* src = sel == 0 ? w0 : sel == 1 ? w1 : sel == 2 ? w2 : w3;
    const int i = (blk & 1023) * 256 + threadIdx.x;
    f32x4 v = ((const f32x4*)src)[i];
    short4v o;
    o[0] = bf16_bits(v[0]); o[1] = bf16_bits(v[1]);
    o[2] = bf16_bits(v[2]); o[3] = bf16_bits(v[3]);
    ((short4v*)(dst + (size_t)sel * kD * kD))[i] = o;
}

// Fused x + all-4-weights fp32->bf16 conversion in ONE launch. Grid 12288:
// blocks [0,8192) convert x (8.4M elems), [8192,12288) the 4 weight mats.
__global__ __launch_bounds__(256) void cvt_all(
    const float* __restrict__ x,
    const float* __restrict__ w0, const float* __restrict__ w1,
    const float* __restrict__ w2, const float* __restrict__ w3,
    __hip_bfloat16* __restrict__ xb, __hip_bfloat16* __restrict__ wdst)
{
    int blk = blockIdx.x;
    const float* src;
    __hip_bfloat16* dst;
    int i;
    if (blk < 8192) {
        src = x; dst = xb; i = blk * 256 + threadIdx.x;
    } else {
        blk -= 8192;
        const int sel = blk >> 10;
        src = sel == 0 ? w0 : sel == 1 ? w1 : sel == 2 ? w2 : w3;
        dst = wdst + (size_t)sel * kD * kD;
        i = (blk & 1023) * 256 + threadIdx.x;
    }
    f32x4 v = ((const f32x4*)src)[i];
    short4v o;
    o[0] = bf16_bits(v[0]); o[1] = bf16_bits(v[1]);
    o[2] = bf16_bits(v[2]); o[3] = bf16_bits(v[3]);
    ((short4v*)dst)[i] = o;
}

// ===========================================================================
// FAST PATH (ws >= 88MB)
// ===========================================================================

// Fused Q/K/V projection, 128x128 tiles, BK=64, GLDS staging + XOR swizzle.
__global__ __launch_bounds__(256) void gemm_qkv(
    const __hip_bfloat16* __restrict__ X, const __hip_bfloat16* __restrict__ Wb,
    const float* __restrict__ bq, const float* __restrict__ bk,
    const float* __restrict__ bv,
    __hip_bfloat16* __restrict__ Qw, __hip_bfloat16* __restrict__ Kw,
    __hip_bfloat16* __restrict__ Vtw)
{
    __shared__ short As[128 * 64];
    __shared__ short Bs[128 * 64];

    const int lane = threadIdx.x & 63, wave = threadIdx.x >> 6;
    const int quad = lane >> 4, l16 = lane & 15;
    const int sel = blockIdx.y >> 3;              // 0=Q 1=K 2=V
    const int m0 = blockIdx.x * 128, n0 = (blockIdx.y & 7) * 128;
    const int wm = wave & 1, wn = wave >> 1;

    const float* bias = sel == 0 ? bq : sel == 1 ? bk : bv;
    const short* Xg = (const short*)X + (size_t)m0 * kD;
    const short* Wg = (const short*)Wb + (size_t)sel * kD * kD + (size_t)n0 * kD;

    f32x4 acc[4][4];
    #pragma unroll
    for (int mt = 0; mt < 4; ++mt)
        #pragma unroll
        for (int nt = 0; nt < 4; ++nt) acc[mt][nt] = f32x4{0.f, 0.f, 0.f, 0.f};

    const int srow = lane >> 3;
    const int gch  = (lane & 7) ^ srow;

    for (int k0 = 0; k0 < kD; k0 += 64) {
        __syncthreads();
        #pragma unroll
        for (int i = 0; i < 4; ++i) {
            const int rowbase = wave * 32 + i * 8;
            const int row = rowbase + srow;
            GLDS16(Xg + (size_t)row * kD + k0 + gch * 8, &As[rowbase * 64]);
            GLDS16(Wg + (size_t)row * kD + k0 + gch * 8, &Bs[rowbase * 64]);
        }
        __syncthreads();

        #pragma unroll
        for (int c = 0; c < 2; ++c) {
            short8 af[4], bf[4];
            const int rx = l16 & 7;
            #pragma unroll
            for (int mt = 0; mt < 4; ++mt)
                af[mt] = *(const short8*)&As[(wm * 64 + mt * 16 + l16) * 64
                                             + (((c * 4 + quad) ^ rx) * 8)];
            #pragma unroll
            for (int nt = 0; nt < 4; ++nt)
                bf[nt] = *(const short8*)&Bs[(wn * 64 + nt * 16 + l16) * 64
                                             + (((c * 4 + quad) ^ rx) * 8)];
            #pragma unroll
            for (int mt = 0; mt < 4; ++mt)
                #pragma unroll
                for (int nt = 0; nt < 4; ++nt)
                    acc[mt][nt] = MFMA16(af[mt], bf[nt], acc[mt][nt]);
        }
    }

    #pragma unroll
    for (int nt = 0; nt < 4; ++nt) {
        const int n = n0 + wn * 64 + nt * 16 + l16;
        const float bvv = bias[n];
        #pragma unroll
        for (int mt = 0; mt < 4; ++mt) {
            if (sel == 2) {
                const int m = m0 + wm * 64 + mt * 16 + quad * 4;
                short4v pk;
                #pragma unroll
                for (int r = 0; r < 4; ++r)
                    pk[r] = bf16_bits(acc[mt][nt][r] + bvv);
                const int bh2 = (m >> 12) * kH + (n >> 6);
                short* dst = (short*)Vtw
                    + ((size_t)bh2 * kHD + (size_t)(n & (kHD - 1))) * kS
                    + (size_t)(m & (kS - 1));
                *(short4v*)dst = pk;
            } else {
                __hip_bfloat16* dst = sel == 0 ? Qw : Kw;
                const float scale = sel == 0 ? 0.18033688f : 1.0f;  // 0.125*log2e
                #pragma unroll
                for (int r = 0; r < 4; ++r) {
                    const int m = m0 + wm * 64 + mt * 16 + quad * 4 + r;
                    const float v = (acc[mt][nt][r] + bvv) * scale;
                    const size_t addr = (((size_t)(m >> 12) * kH + (n >> 6)) * kS
                                         + (size_t)(m & (kS - 1))) * kHD
                                        + (size_t)(n & (kHD - 1));
                    dst[addr] = __float2bfloat16(v);
                }
            }
        }
    }
}

// Output projection: out(fp32) = O(bf16) @ Wo.T + bo. 128x128 tiles.
__global__ __launch_bounds__(256) void gemm_out(
    const __hip_bfloat16* __restrict__ X, const __hip_bfloat16* __restrict__ W,
    const float* __restrict__ bias, float* __restrict__ out)
{
    __shared__ short As[128 * 64];
    __shared__ short Bs[128 * 64];

    const int lane = threadIdx.x & 63, wave = threadIdx.x >> 6;
    const int quad = lane >> 4, l16 = lane & 15;
    const int m0 = blockIdx.x * 128, n0 = blockIdx.y * 128;
    const int wm = wave & 1, wn = wave >> 1;

    const short* Xg = (const short*)X + (size_t)m0 * kD;
    const short* Wg = (const short*)W + (size_t)n0 * kD;

    f32x4 acc[4][4];
    #pragma unroll
    for (int mt = 0; mt < 4; ++mt)
        #pragma unroll
        for (int nt = 0; nt < 4; ++nt) acc[mt][nt] = f32x4{0.f, 0.f, 0.f, 0.f};

    const int srow = lane >> 3;
    const int gch  = (lane & 7) ^ srow;

    for (int k0 = 0; k0 < kD; k0 += 64) {
        __syncthreads();
        #pragma unroll
        for (int i = 0; i < 4; ++i) {
            const int rowbase = wave * 32 + i * 8;
            const int row = rowbase + srow;
            GLDS16(Xg + (size_t)row * kD + k0 + gch * 8, &As[rowbase * 64]);
            GLDS16(Wg + (size_t)row * kD + k0 + gch * 8, &Bs[rowbase * 64]);
        }
        __syncthreads();

        #pragma unroll
        for (int c = 0; c < 2; ++c) {
            short8 af[4], bf[4];
            const int rx = l16 & 7;
            #pragma unroll
            for (int mt = 0; mt < 4; ++mt)
                af[mt] = *(const short8*)&As[(wm * 64 + mt * 16 + l16) * 64
                                             + (((c * 4 + quad) ^ rx) * 8)];
            #pragma unroll
            for (int nt = 0; nt < 4; ++nt)
                bf[nt] = *(const short8*)&Bs[(wn * 64 + nt * 16 + l16) * 64
                                             + (((c * 4 + quad) ^ rx) * 8)];
            #pragma unroll
            for (int mt = 0; mt < 4; ++mt)
                #pragma unroll
                for (int nt = 0; nt < 4; ++nt)
                    acc[mt][nt] = MFMA16(af[mt], bf[nt], acc[mt][nt]);
        }
    }

    #pragma unroll
    for (int nt = 0; nt < 4; ++nt) {
        const int n = n0 + wn * 64 + nt * 16 + l16;
        const float bv = bias[n];
        #pragma unroll
        for (int mt = 0; mt < 4; ++mt)
            #pragma unroll
            for (int r = 0; r < 4; ++r) {
                const int m = m0 + wm * 64 + mt * 16 + quad * 4 + r;
                out[(size_t)m * kD + n] = acc[mt][nt][r] + bv;
            }
    }
}

// Flash attention v7. Qw pre-scaled by 0.125*log2e; Kw [BH][S][64]; Vt [BH][64][S].
// R5's T=4 permuted-K fragment staging, with two instruction-count reductions
// (R5 post-mortem: per-SIMD issue/serial-chain bound, invariant to occupancy,
// conflicts, and pipelining — so shrink the bill):
//  * KVBLK=128: 32 tiles instead of 64 -> barriers, GLDS rounds, and loop
//    overhead halved; prefetch slack doubled. LDS 64KB, still 2 blocks/CU.
//  * lsum on VALU (psum adds, ~96/tile on an idle pipe) instead of 4 ones-
//    MFMAs per 64-kv: per-wave MFMA count 4608 -> 4096 (-11%).
//    Epilogue redistributes row sums via 2x shfl_xor + shfl (R2-verified).
__global__ __launch_bounds__(256, 2) void flash2(
    const __hip_bfloat16* __restrict__ Qw, const __hip_bfloat16* __restrict__ Kw,
    const __hip_bfloat16* __restrict__ Vt, __hip_bfloat16* __restrict__ O)
{
    __shared__ short Ks[2][16 * 512];   // 16 fragment blocks of 1KB per buffer
    __shared__ short Vs[2][16 * 512];

    const int lane = threadIdx.x & 63, wave = threadIdx.x >> 6;
    const int quad = lane >> 4, l16 = lane & 15;

    // XCD-aware swizzle: 512 blocks, 8 XCDs -> contiguous 64-block chunks
    // (= 4 bh per XCD -> K/V working set 4MB = one L2).
    const int flat = blockIdx.y * 16 + blockIdx.x;
    const int swz  = (flat & 7) * 64 + (flat >> 3);
    const int bh = swz >> 4, b = bh >> 4, h = bh & 15;
    const int qbase = (swz & 15) * 256 + wave * 64;

    const short* Qg = (const short*)Qw + ((size_t)bh * kS + qbase) * kHD;
    short8 qf[4][2];
    #pragma unroll
    for (int t = 0; t < 4; ++t)
        #pragma unroll
        for (int c = 0; c < 2; ++c)
            qf[t][c] = *(const short8*)(Qg + (t * 16 + l16) * kHD + c * 32 + quad * 8);

    const short* Kg = (const short*)Kw + (size_t)bh * kS * kHD;
    const short* Vg = (const short*)Vt + (size_t)bh * kHD * kS;

    f32x4 o[4][4];
    float psum[4] = {0.f, 0.f, 0.f, 0.f};
    #pragma unroll
    for (int t = 0; t < 4; ++t)
        #pragma unroll
        for (int dt = 0; dt < 4; ++dt) o[t][dt] = f32x4{0.f, 0.f, 0.f, 0.f};

    // --- per-wave staging (KVBLK=128: 16 K frags + 16 V frags, 4+4 per wave) ---
    // K frag f = c*4 + m*2 + dhalf; wave w stages f = w*4+i (i.e. c == w):
    //   lane (l16,quad) sources K[row = w*32 + 8*(l16>>2) + 4m + (l16&3)]
    //                            [d = dhalf*32 + quad*8 .. +7]  (permuted rows)
    // V frag f = c*4 + dt; wave w stages f = w*4+i (c == w, dt == i):
    //   lane (l16,quad) sources Vt[d = i*16 + l16][s = w*32 + quad*8 ..]
    const short* ka = Kg + (size_t)(wave * 32 + 8 * (l16 >> 2) + (l16 & 3)) * kHD
                    + quad * 8;
    const short* va = Vg + (size_t)l16 * kS + wave * 32 + quad * 8;

    // prefetch tile 0 (fragment order)
    #pragma unroll
    for (int i = 0; i < 4; ++i) {
        GLDS16(ka + (size_t)((i >> 1) * 4) * kHD + (i & 1) * 32,
               &Ks[0][(wave * 4 + i) * 512]);
        GLDS16(va + (size_t)(i * 16) * kS, &Vs[0][(wave * 4 + i) * 512]);
    }
    ka += 128 * kHD; va += 128;

    for (int k0 = 0; k0 < kS; k0 += 128) {
        const int cur = (k0 >> 7) & 1;
        __syncthreads();   // drains in-flight GLDS + guards buffer reuse
        if (k0 + 128 < kS) {
            const int nxt = cur ^ 1;
            #pragma unroll
            for (int i = 0; i < 4; ++i) {
                GLDS16(ka + (size_t)((i >> 1) * 4) * kHD + (i & 1) * 32,
                       &Ks[nxt][(wave * 4 + i) * 512]);
                GLDS16(va + (size_t)(i * 16) * kS, &Vs[nxt][(wave * 4 + i) * 512]);
            }
            ka += 128 * kHD; va += 128;
        }

        // per 32-wide k-half: QK^T (+exp, pack directly into PV-A order) -> PV.
        #pragma unroll
        for (int c = 0; c < 4; ++c) {
            // V fragments early: LDS latency hides under the QK MFMAs.
            short8 vb[4];
            #pragma unroll
            for (int dt = 0; dt < 4; ++dt)
                vb[dt] = *(const short8*)&Vs[cur][(c * 4 + dt) * 512 + lane * 8];

            unsigned int P[4][4];
            #pragma unroll
            for (int m = 0; m < 2; ++m) {
                const int fb = c * 4 + m * 2;
                short8 a0 = *(const short8*)&Ks[cur][(fb + 0) * 512 + lane * 8];
                short8 a1 = *(const short8*)&Ks[cur][(fb + 1) * 512 + lane * 8];
                #pragma unroll
                for (int t = 0; t < 4; ++t) {
                    f32x4 z = {0.f, 0.f, 0.f, 0.f};
                    f32x4 s = MFMA16(a0, qf[t][0], z);
                    s = MFMA16(a1, qf[t][1], s);
                    // lane ends with khalf = 8*quad + 4m + r  (PV-A order)
                    const float e0 = __builtin_amdgcn_exp2f(s[0]);
                    const float e1 = __builtin_amdgcn_exp2f(s[1]);
                    const float e2 = __builtin_amdgcn_exp2f(s[2]);
                    const float e3 = __builtin_amdgcn_exp2f(s[3]);
                    psum[t] += (e0 + e1) + (e2 + e3);
                    P[t][m * 2 + 0] = pk_bf16(e0, e1);
                    P[t][m * 2 + 1] = pk_bf16(e2, e3);
                }
            }

            short8 pa[4];
            #pragma unroll
            for (int t = 0; t < 4; ++t) {
                uint4v u = {P[t][0], P[t][1], P[t][2], P[t][3]};
                pa[t] = __builtin_bit_cast(short8, u);
            }

            __builtin_amdgcn_s_setprio(1);
            #pragma unroll
            for (int dt = 0; dt < 4; ++dt)
                #pragma unroll
                for (int t = 0; t < 4; ++t)
                    o[t][dt] = MFMA16(pa[t], vb[dt], o[t][dt]);
            __builtin_amdgcn_s_setprio(0);
        }
    }

    // ---- epilogue: row-sum redistribution + /l, store [B,S,D] bf16 ----
    // psum[t] at lane (l16,quad) covers k%32 slots {8*quad+4m+r}; xor-reduce
    // over quad lanes gives the full row sum for q-row l16; then shfl moves
    // L(q = quad*4+r) to every lane (o rows are q = quad*4+r).
    #pragma unroll
    for (int t = 0; t < 4; ++t) {
        float L = psum[t];
        L += __shfl_xor(L, 16, 64);
        L += __shfl_xor(L, 32, 64);
        #pragma unroll
        for (int r = 0; r < 4; ++r) {
            const float Lr = __shfl(L, quad * 4 + r, 64);  // row q = quad*4+r
            const float inv = 1.0f / Lr;
            const int sq = qbase + t * 16 + quad * 4 + r;
            #pragma unroll
            for (int dt = 0; dt < 4; ++dt)
                O[((size_t)b * kS + sq) * kD + h * kHD + dt * 16 + l16] =
                    __float2bfloat16(o[t][dt][r] * inv);
        }
    }
}

// ===========================================================================
// FALLBACK PATH (round-8 structure) — unchanged
// ===========================================================================
template <bool KV8, bool WB16>
__global__ __launch_bounds__(256) void gemm_kv(
    const float* __restrict__ X, const void* __restrict__ W,
    const float* __restrict__ bias, void* __restrict__ outv)
{
    const int lane = threadIdx.x & 63;
    const int wave = threadIdx.x >> 6;
    const int quad = lane >> 4;
    const int l16  = lane & 15;
    const int m0 = blockIdx.x * 16;
    const int n0 = blockIdx.y * 256 + wave * 64;

    const float* xr = X + (size_t)(m0 + l16) * kD;
    const float* wf = (const float*)W + (size_t)(n0 + l16) * kD;
    const short* wb = (const short*)W + (size_t)(n0 + l16) * kD;

    f32x4 acc[4] = {{0.f,0.f,0.f,0.f},{0.f,0.f,0.f,0.f},
                    {0.f,0.f,0.f,0.f},{0.f,0.f,0.f,0.f}};

    for (int k8 = quad; k8 < kD / 8; k8 += 4) {
        short8 a = cvt8(xr + k8 * 8);
        #pragma unroll
        for (int nt = 0; nt < 4; ++nt) {
            short8 w = WB16 ? *(const short8*)(wb + nt * 16 * kD + k8 * 8)
                            : cvt8(wf + nt * 16 * kD + k8 * 8);
            acc[nt] = MFMA16(a, w, acc[nt]);
        }
    }

    #pragma unroll
    for (int nt = 0; nt < 4; ++nt) {
        const int n = n0 + nt * 16 + l16;
        const float bv = bias[n];
        #pragma unroll
        for (int r = 0; r < 4; ++r) {
            const int m = m0 + quad * 4 + r;
            const float v = acc[nt][r] + bv;
            const size_t addr = (((size_t)(m >> 12) * kH + (n >> 6)) * kS
                                 + (size_t)(m & (kS - 1))) * kHD + (size_t)(n & (kHD - 1));
            if (KV8) ((unsigned char*)outv)[addr] = f32_to_e4m3(v);
            else     ((__hip_bfloat16*)outv)[addr] = __float2bfloat16(v);
        }
    }
}

template <bool KV8, bool WB16>
__global__ __launch_bounds__(256) void flash_fusedq(
    const float* __restrict__ x,  const void* __restrict__ Wq,
    const float* __restrict__ bq, const void* __restrict__ Kw,
    const void* __restrict__ Vw,  __hip_bfloat16* __restrict__ O)
{
    __shared__ short pool[9216];
    __shared__ short Ps[4][32][72];

    const int lane = threadIdx.x & 63;
    const int wave = threadIdx.x >> 6;
    const int quad = lane >> 4;
    const int l16  = lane & 15;
    const int bh   = blockIdx.y;
    const int b    = bh >> 4, h = bh & 15;
    const int qbase = blockIdx.x * 128 + wave * 32;

    {
        const float* xr0 = x + (size_t)(b * kS + qbase + l16) * kD;
        const float* xr1 = xr0 + (size_t)16 * kD;
        const float* wqf = (const float*)Wq + (size_t)(h * kHD + l16) * kD;
        const short* wqb = (const short*)Wq + (size_t)(h * kHD + l16) * kD;
        f32x4 qa[2][4];
        #pragma unroll
        for (int t = 0; t < 2; ++t)
            #pragma unroll
            for (int nt = 0; nt < 4; ++nt) qa[t][nt] = f32x4{0.f,0.f,0.f,0.f};

        for (int k8 = quad; k8 < kD / 8; k8 += 4) {
            short8 a0 = cvt8(xr0 + k8 * 8);
            short8 a1 = cvt8(xr1 + k8 * 8);
            #pragma unroll
            for (int nt = 0; nt < 4; ++nt) {
                short8 w = WB16 ? *(const short8*)(wqb + nt * 16 * kD + k8 * 8)
                                : cvt8(wqf + nt * 16 * kD + k8 * 8);
                qa[0][nt] = MFMA16(a0, w, qa[0][nt]);
                qa[1][nt] = MFMA16(a1, w, qa[1][nt]);
            }
        }
        #pragma unroll
        for (int t = 0; t < 2; ++t)
            #pragma unroll
            for (int nt = 0; nt < 4; ++nt) {
                const float bv = bq[h * kHD + nt * 16 + l16];
                #pragma unroll
                for (int r = 0; r < 4; ++r)
                    pool[wave * 2304 + (t * 16 + quad * 4 + r) * 72 + nt * 16 + l16] =
                        bf16_bits((qa[t][nt][r] + bv) * 0.125f);
            }
    }
    short8 qf[2][2];
    #pragma unroll
    for (int t = 0; t < 2; ++t)
        #pragma unroll
        for (int c = 0; c < 2; ++c)
            qf[t][c] = *(const short8*)&pool[wave * 2304 + (t * 16 + l16) * 72 + c * 32 + quad * 8];

    f32x4 o[2][4];
    float mrow[2][4], lrow[2][4];
    #pragma unroll
    for (int t = 0; t < 2; ++t)
        #pragma unroll
        for (int dt = 0; dt < 4; ++dt) o[t][dt] = f32x4{0.f,0.f,0.f,0.f};
    #pragma unroll
    for (int t = 0; t < 2; ++t)
        #pragma unroll
        for (int r = 0; r < 4; ++r) { mrow[t][r] = -INFINITY; lrow[t][r] = 0.f; }

    const __hip_bfloat16* Kb16 = (const __hip_bfloat16*)Kw + (size_t)bh * kS * kHD;
    const __hip_bfloat16* Vb16 = (const __hip_bfloat16*)Vw + (size_t)bh * kS * kHD;
    const unsigned char*  K8   = (const unsigned char*)Kw + (size_t)bh * kS * kHD;
    const unsigned char*  V8   = (const unsigned char*)Vw + (size_t)bh * kS * kHD;

    for (int k0 = 0; k0 < kS; k0 += 64) {
        __syncthreads();
        #pragma unroll
        for (int i = 0; i < 2; ++i) {
            const int lin = threadIdx.x + i * 256;
            const int kr = lin >> 3, c8 = lin & 7;
            short8 kv, vv;
            if (KV8) {
                uint2 kbits = *(const uint2*)(K8 + (size_t)(k0 + kr) * kHD + c8 * 8);
                uint2 vbits = *(const uint2*)(V8 + (size_t)(k0 + kr) * kHD + c8 * 8);
                #pragma unroll
                for (int j = 0; j < 4; ++j) {
                    kv[j]     = bf16_bits(e4m3_to_f32((kbits.x >> (8 * j)) & 255u));
                    kv[4 + j] = bf16_bits(e4m3_to_f32((kbits.y >> (8 * j)) & 255u));
                    vv[j]     = bf16_bits(e4m3_to_f32((vbits.x >> (8 * j)) & 255u));
                    vv[4 + j] = bf16_bits(e4m3_to_f32((vbits.y >> (8 * j)) & 255u));
                }
            } else {
                kv = *(const short8*)(Kb16 + (size_t)(k0 + kr) * kHD + c8 * 8);
                vv = *(const short8*)(Vb16 + (size_t)(k0 + kr) * kHD + c8 * 8);
            }
            *(short8*)&pool[kr * 72 + c8 * 8] = kv;
            #pragma unroll
            for (int j = 0; j < 8; ++j)
                pool[4608 + (c8 * 8 + j) * 72 + (((kr >> 3) ^ c8) << 3) + (kr & 7)] = vv[j];
        }
        __syncthreads();

        f32x4 sc[2][4];
        #pragma unroll
        for (int kt = 0; kt < 4; ++kt) {
            short8 b0 = *(const short8*)&pool[(kt * 16 + l16) * 72 + quad * 8];
            short8 b1 = *(const short8*)&pool[(kt * 16 + l16) * 72 + 32 + quad * 8];
            f32x4 z = {0.f, 0.f, 0.f, 0.f};
            f32x4 s0 = MFMA16(qf[0][0], b0, z); s0 = MFMA16(qf[0][1], b1, s0);
            f32x4 s1 = MFMA16(qf[1][0], b0, z); s1 = MFMA16(qf[1][1], b1, s1);
            sc[0][kt] = s0; sc[1][kt] = s1;
        }

        #pragma unroll
        for (int t = 0; t < 2; ++t)
            #pragma unroll
            for (int r = 0; r < 4; ++r) {
                float s0 = sc[t][0][r], s1 = sc[t][1][r];
                float s2 = sc[t][2][r], s3 = sc[t][3][r];
                float mx = fmaxf(fmaxf(s0, s1), fmaxf(s2, s3));
                #pragma unroll
                for (int off = 1; off < 16; off <<= 1)
                    mx = fmaxf(mx, __shfl_xor(mx, off, 64));
                const float mnew  = fmaxf(mrow[t][r], mx);
                const float alpha = __builtin_amdgcn_exp2f((mrow[t][r] - mnew) * 1.44269504f);
                mrow[t][r] = mnew;
                const float p0 = __builtin_amdgcn_exp2f((s0 - mnew) * 1.44269504f);
                const float p1 = __builtin_amdgcn_exp2f((s1 - mnew) * 1.44269504f);
                const float p2 = __builtin_amdgcn_exp2f((s2 - mnew) * 1.44269504f);
                const float p3 = __builtin_amdgcn_exp2f((s3 - mnew) * 1.44269504f);
                float ps = (p0 + p1) + (p2 + p3);
                #pragma unroll
                for (int off = 1; off < 16; off <<= 1)
                    ps += __shfl_xor(ps, off, 64);
                lrow[t][r] = lrow[t][r] * alpha + ps;
                o[t][0][r] *= alpha; o[t][1][r] *= alpha;
                o[t][2][r] *= alpha; o[t][3][r] *= alpha;
                const int row = t * 16 + quad * 4 + r;
                Ps[wave][row][l16]      = bf16_bits(p0);
                Ps[wave][row][16 + l16] = bf16_bits(p1);
                Ps[wave][row][32 + l16] = bf16_bits(p2);
                Ps[wave][row][48 + l16] = bf16_bits(p3);
            }

        short8 pa[2][2];
        #pragma unroll
        for (int t = 0; t < 2; ++t)
            #pragma unroll
            for (int c = 0; c < 2; ++c)
                pa[t][c] = *(const short8*)&Ps[wave][t * 16 + l16][c * 32 + quad * 8];
        #pragma unroll
        for (int c = 0; c < 2; ++c)
            #pragma unroll
            for (int dt = 0; dt < 4; ++dt) {
                const int d = dt * 16 + l16;
                short8 vb = *(const short8*)&pool[4608 + d * 72 + ((((c * 4 + quad)) ^ (d >> 3)) << 3)];
                o[0][dt] = MFMA16(pa[0][c], vb, o[0][dt]);
                o[1][dt] = MFMA16(pa[1][c], vb, o[1][dt]);
            }
    }

    #pragma unroll
    for (int t = 0; t < 2; ++t)
        #pragma unroll
        for (int r = 0; r < 4; ++r) {
            const float inv = 1.0f / lrow[t][r];
            const int sq = qbase + t * 16 + quad * 4 + r;
            #pragma unroll
            for (int dt = 0; dt < 4; ++dt)
                O[((size_t)b * kS + sq) * kD + h * kHD + dt * 16 + l16] =
                    __float2bfloat16(o[t][dt][r] * inv);
        }
}

template <bool WB16>
__global__ __launch_bounds__(256) void proj_out(
    const __hip_bfloat16* __restrict__ Xb, const void* __restrict__ W,
    const float* __restrict__ bias, float* __restrict__ out)
{
    const int lane = threadIdx.x & 63;
    const int wave = threadIdx.x >> 6;
    const int quad = lane >> 4;
    const int l16  = lane & 15;
    const int m0 = blockIdx.x * 16;
    const int n0 = blockIdx.y * 256 + wave * 64;

    const short8* xr = (const short8*)((const short*)Xb + (size_t)(m0 + l16) * kD);
    const float*  wf = (const float*)W + (size_t)(n0 + l16) * kD;
    const short*  wb = (const short*)W + (size_t)(n0 + l16) * kD;

    f32x4 acc[4] = {{0.f,0.f,0.f,0.f},{0.f,0.f,0.f,0.f},
                    {0.f,0.f,0.f,0.f},{0.f,0.f,0.f,0.f}};

    for (int k8 = quad; k8 < kD / 8; k8 += 4) {
        short8 a = xr[k8];
        #pragma unroll
        for (int nt = 0; nt < 4; ++nt) {
            short8 w = WB16 ? *(const short8*)(wb + nt * 16 * kD + k8 * 8)
                            : cvt8(wf + nt * 16 * kD + k8 * 8);
            acc[nt] = MFMA16(a, w, acc[nt]);
        }
    }

    #pragma unroll
    for (int nt = 0; nt < 4; ++nt) {
        const int n = n0 + nt * 16 + l16;
        const float bv = bias[n];
        #pragma unroll
        for (int r = 0; r < 4; ++r) {
            const int m = m0 + quad * 4 + r;
            out[(size_t)m * kD + n] = acc[nt][r] + bv;
        }
    }
}

extern "C" void kernel_launch(void* const* d_in, const int* in_sizes, int n_in,
                              void* d_out, int out_size, void* d_ws, size_t ws_size,
                              hipStream_t stream)
{
    const float* x = nullptr;
    const float* Wm[4] = {nullptr, nullptr, nullptr, nullptr};
    const float* bm[4] = {nullptr, nullptr, nullptr, nullptr};
    int wi = 0, bi = 0;
    for (int i = 0; i < n_in; ++i) {
        const int s = in_sizes[i];
        if      (s == 2 * kS * kD)         x = (const float*)d_in[i];
        else if (s == kD * kD && wi < 4)   Wm[wi++] = (const float*)d_in[i];
        else if (s == kD      && bi < 4)   bm[bi++] = (const float*)d_in[i];
    }
    const float *Wq = Wm[0], *Wk = Wm[1], *Wv = Wm[2], *Wo = Wm[3];
    const float *bq = bm[0], *bk = bm[1], *bv = bm[2], *bo = bm[3];
    float* out = (float*)d_out;   // output is fp32

    const size_t elems = (size_t)2 * kS * kD;   // 8,388,608
    const size_t wel   = (size_t)kD * kD;       // 1,048,576
    const size_t MB = 1024 * 1024;
    dim3 bb(256);

    if (ws_size >= 88 * MB) {
        // xb(16) | Qw(16) | Kw(16) | Vt(16) | Ow(16) | 4x Wb(8) = 88MB
        __hip_bfloat16* xb  = (__hip_bfloat16*)d_ws;
        __hip_bfloat16* Qw  = xb + elems;
        __hip_bfloat16* Kw  = Qw + elems;
        __hip_bfloat16* Vtw = Kw + elems;
        __hip_bfloat16* Ow  = Vtw + elems;
        __hip_bfloat16* Wqb = Ow + elems;     // W q/k/v/o contiguous
        __hip_bfloat16* Wob = Wqb + 3 * wel;

        cvt_all<<<dim3(12288), bb, 0, stream>>>(x, Wq, Wk, Wv, Wo, xb, Wqb);

        gemm_qkv<<<dim3(64, 24), bb, 0, stream>>>(xb, Wqb, bq, bk, bv, Qw, Kw, Vtw);
        flash2<<<dim3(16, 32), bb, 0, stream>>>(Qw, Kw, Vtw, Ow);
        gemm_out<<<dim3(64, 8), bb, 0, stream>>>(Ow, Wob, bo, out);
        return;
    }

    dim3 gg(512, 4), gf(kS / 128, 2 * kH);
    if (ws_size >= 56 * MB) {
        __hip_bfloat16* Kw  = (__hip_bfloat16*)d_ws;
        __hip_bfloat16* Vw  = Kw + elems;
        __hip_bfloat16* Ow  = Vw + elems;
        __hip_bfloat16* Wqb = Ow + elems;
        __hip_bfloat16* Wkb = Wqb + wel;
        __hip_bfloat16* Wvb = Wkb + wel;
        __hip_bfloat16* Wob = Wvb + wel;
        cvt_w4<<<dim3(4096), bb, 0, stream>>>(Wq, Wk, Wv, Wo, Wqb);
        gemm_kv<false, true><<<gg, bb, 0, stream>>>(x, Wkb, bk, Kw);
        gemm_kv<false, true><<<gg, bb, 0, stream>>>(x, Wvb, bv, Vw);
        flash_fusedq<false, true><<<gf, bb, 0, stream>>>(x, Wqb, bq, Kw, Vw, Ow);
        proj_out<true><<<gg, bb, 0, stream>>>(Ow, Wob, bo, out);
    } else if (ws_size >= 48 * MB) {
        __hip_bfloat16* Kw = (__hip_bfloat16*)d_ws;
        __hip_bfloat16* Vw = Kw + elems;
        __hip_bfloat16* Ow = Vw + elems;
        gemm_kv<false, false><<<gg, bb, 0, stream>>>(x, Wk, bk, Kw);
        gemm_kv<false, false><<<gg, bb, 0, stream>>>(x, Wv, bv, Vw);
        flash_fusedq<false, false><<<gf, bb, 0, stream>>>(x, Wq, bq, Kw, Vw, Ow);
        proj_out<false><<<gg, bb, 0, stream>>>(Ow, Wo, bo, out);
    } else {
        unsigned char* Kw = (unsigned char*)d_ws;
        unsigned char* Vw = Kw + elems;
        __hip_bfloat16* Ow = (__hip_bfloat16*)(Vw + elems);
        gemm_kv<true, false><<<gg, bb, 0, stream>>>(x, Wk, bk, Kw);
        gemm_kv<true, false><<<gg, bb, 0, stream>>>(x, Wv, bv, Vw);
        flash_fusedq<true, false><<<gf, bb, 0, stream>>>(x, Wq, bq, Kw, Vw, Ow);
        proj_out<false><<<gg, bb, 0, stream>>>(Ow, Wo, bo, out);
    }
}

// Round 7
// 322.894 us; speedup vs baseline: 1.1137x; 1.1137x over previous
//
#include <hip/hip_runtime.h>
#include <hip/hip_bf16.h>
#include <stdint.h>

typedef __attribute__((ext_vector_type(8))) short short8;
typedef __attribute__((ext_vector_type(4))) short short4v;
typedef __attribute__((ext_vector_type(4))) float f32x4;
typedef __attribute__((ext_vector_type(4))) unsigned int uint4v;

#define MFMA16(A, B, C) __builtin_amdgcn_mfma_f32_16x16x32_bf16(A, B, C, 0, 0, 0)

// async global->LDS, 16B/lane: LDS dest = wave-uniform base + lane*16
#define GLDS16(gp, lp) __builtin_amdgcn_global_load_lds(                     \
    (const __attribute__((address_space(1))) unsigned int*)(gp),             \
    (__attribute__((address_space(3))) unsigned int*)(lp), 16, 0, 0)

static constexpr int kS  = 4096;
static constexpr int kD  = 1024;
static constexpr int kH  = 16;
static constexpr int kHD = 64;

__device__ __forceinline__ short bf16_bits(float f) {
    __hip_bfloat16 h = __float2bfloat16(f);
    return *(short*)&h;
}

// packed 2x fp32 -> bf16x2 (v_cvt_pk_bf16_f32)
__device__ __forceinline__ unsigned int pk_bf16(float a, float b) {
    __hip_bfloat162 h = __float22bfloat162_rn(make_float2(a, b));
    return *(unsigned int*)&h;
}

__device__ __forceinline__ short8 cvt8(const float* __restrict__ p) {
    f32x4 a = ((const f32x4*)p)[0];
    f32x4 b = ((const f32x4*)p)[1];
    short8 r;
    r[0] = bf16_bits(a[0]); r[1] = bf16_bits(a[1]);
    r[2] = bf16_bits(a[2]); r[3] = bf16_bits(a[3]);
    r[4] = bf16_bits(b[0]); r[5] = bf16_bits(b[1]);
    r[6] = bf16_bits(b[2]); r[7] = bf16_bits(b[3]);
    return r;
}

// ---- fp8 e4m3fn (fallback tier only) ----
__device__ __forceinline__ unsigned char f32_to_e4m3(float f) {
    unsigned int u = __float_as_uint(f);
    unsigned int s = (u >> 24) & 0x80u;
    unsigned int a = u & 0x7fffffffu;
    if (a < 0x3c800000u) {
        float af = __uint_as_float(a);
        unsigned int sub = (unsigned int)(af * 512.0f + 0.5f);
        return (unsigned char)(s | sub);
    }
    unsigned int r = a + 0x80000u;
    unsigned int m = (r >> 20) & 7u;
    int eb = (int)(r >> 23) - 127 + 7;
    unsigned int bits = ((unsigned int)eb << 3) | m;
    if (bits > 0x7Eu) bits = 0x7Eu;
    return (unsigned char)(s | bits);
}
__device__ __forceinline__ float e4m3_to_f32(unsigned int b) {
    unsigned int s = b & 0x80u;
    unsigned int e = (b >> 3) & 15u;
    unsigned int m = b & 7u;
    float f = e ? __uint_as_float(((e + 120u) << 23) | (m << 20))
                : (float)m * 0.001953125f;
    return s ? -f : f;
}

// fp32 -> bf16, 4/thread; launch with n/1024 blocks.
__global__ __launch_bounds__(256) void cvt_f32_bf16(
    const float* __restrict__ src, __hip_bfloat16* __restrict__ dst)
{
    const int i = blockIdx.x * 256 + threadIdx.x;
    f32x4 v = ((const f32x4*)src)[i];
    short4v o;
    o[0] = bf16_bits(v[0]); o[1] = bf16_bits(v[1]);
    o[2] = bf16_bits(v[2]); o[3] = bf16_bits(v[3]);
    ((short4v*)dst)[i] = o;
}

// 4 weight matrices -> one contiguous bf16 dst (each kD*kD). Grid 4096.
__global__ __launch_bounds__(256) void cvt_w4(
    const float* __restrict__ w0, const float* __restrict__ w1,
    const float* __restrict__ w2, const float* __restrict__ w3,
    __hip_bfloat16* __restrict__ dst)
{
    const int blk = blockIdx.x;
    const int sel = blk >> 10;
    const float* src = sel == 0 ? w0 : sel == 1 ? w1 : sel == 2 ? w2 : w3;
    const int i = (blk & 1023) * 256 + threadIdx.x;
    f32x4 v = ((const f32x4*)src)[i];
    short4v o;
    o[0] = bf16_bits(v[0]); o[1] = bf16_bits(v[1]);
    o[2] = bf16_bits(v[2]); o[3] = bf16_bits(v[3]);
    ((short4v*)(dst + (size_t)sel * kD * kD))[i] = o;
}

// Fused x + all-4-weights fp32->bf16 conversion in ONE launch. Grid 12288:
// blocks [0,8192) convert x (8.4M elems), [8192,12288) the 4 weight mats.
__global__ __launch_bounds__(256) void cvt_all(
    const float* __restrict__ x,
    const float* __restrict__ w0, const float* __restrict__ w1,
    const float* __restrict__ w2, const float* __restrict__ w3,
    __hip_bfloat16* __restrict__ xb, __hip_bfloat16* __restrict__ wdst)
{
    int blk = blockIdx.x;
    const float* src;
    __hip_bfloat16* dst;
    int i;
    if (blk < 8192) {
        src = x; dst = xb; i = blk * 256 + threadIdx.x;
    } else {
        blk -= 8192;
        const int sel = blk >> 10;
        src = sel == 0 ? w0 : sel == 1 ? w1 : sel == 2 ? w2 : w3;
        dst = wdst + (size_t)sel * kD * kD;
        i = (blk & 1023) * 256 + threadIdx.x;
    }
    f32x4 v = ((const f32x4*)src)[i];
    short4v o;
    o[0] = bf16_bits(v[0]); o[1] = bf16_bits(v[1]);
    o[2] = bf16_bits(v[2]); o[3] = bf16_bits(v[3]);
    ((short4v*)dst)[i] = o;
}

// ===========================================================================
// FAST PATH (ws >= 88MB)
// ===========================================================================

// Fused Q/K/V projection, 128x128 tiles, BK=64, GLDS staging + XOR swizzle.
// __launch_bounds__(256,4): cap VGPR <=128 so 4 blocks/CU co-reside (32KB LDS
// x4 = 128KB fits) -- multi-block overlap is the m97-structure's stall hider.
__global__ __launch_bounds__(256, 4) void gemm_qkv(
    const __hip_bfloat16* __restrict__ X, const __hip_bfloat16* __restrict__ Wb,
    const float* __restrict__ bq, const float* __restrict__ bk,
    const float* __restrict__ bv,
    __hip_bfloat16* __restrict__ Qw, __hip_bfloat16* __restrict__ Kw,
    __hip_bfloat16* __restrict__ Vtw)
{
    __shared__ short As[128 * 64];
    __shared__ short Bs[128 * 64];

    const int lane = threadIdx.x & 63, wave = threadIdx.x >> 6;
    const int quad = lane >> 4, l16 = lane & 15;
    const int sel = blockIdx.y >> 3;              // 0=Q 1=K 2=V
    const int m0 = blockIdx.x * 128, n0 = (blockIdx.y & 7) * 128;
    const int wm = wave & 1, wn = wave >> 1;

    const float* bias = sel == 0 ? bq : sel == 1 ? bk : bv;
    const short* Xg = (const short*)X + (size_t)m0 * kD;
    const short* Wg = (const short*)Wb + (size_t)sel * kD * kD + (size_t)n0 * kD;

    f32x4 acc[4][4];
    #pragma unroll
    for (int mt = 0; mt < 4; ++mt)
        #pragma unroll
        for (int nt = 0; nt < 4; ++nt) acc[mt][nt] = f32x4{0.f, 0.f, 0.f, 0.f};

    const int srow = lane >> 3;
    const int gch  = (lane & 7) ^ srow;

    for (int k0 = 0; k0 < kD; k0 += 64) {
        __syncthreads();
        #pragma unroll
        for (int i = 0; i < 4; ++i) {
            const int rowbase = wave * 32 + i * 8;
            const int row = rowbase + srow;
            GLDS16(Xg + (size_t)row * kD + k0 + gch * 8, &As[rowbase * 64]);
            GLDS16(Wg + (size_t)row * kD + k0 + gch * 8, &Bs[rowbase * 64]);
        }
        __syncthreads();

        #pragma unroll
        for (int c = 0; c < 2; ++c) {
            short8 af[4], bf[4];
            const int rx = l16 & 7;
            #pragma unroll
            for (int mt = 0; mt < 4; ++mt)
                af[mt] = *(const short8*)&As[(wm * 64 + mt * 16 + l16) * 64
                                             + (((c * 4 + quad) ^ rx) * 8)];
            #pragma unroll
            for (int nt = 0; nt < 4; ++nt)
                bf[nt] = *(const short8*)&Bs[(wn * 64 + nt * 16 + l16) * 64
                                             + (((c * 4 + quad) ^ rx) * 8)];
            #pragma unroll
            for (int mt = 0; mt < 4; ++mt)
                #pragma unroll
                for (int nt = 0; nt < 4; ++nt)
                    acc[mt][nt] = MFMA16(af[mt], bf[nt], acc[mt][nt]);
        }
    }

    #pragma unroll
    for (int nt = 0; nt < 4; ++nt) {
        const int n = n0 + wn * 64 + nt * 16 + l16;
        const float bvv = bias[n];
        #pragma unroll
        for (int mt = 0; mt < 4; ++mt) {
            if (sel == 2) {
                const int m = m0 + wm * 64 + mt * 16 + quad * 4;
                short4v pk;
                #pragma unroll
                for (int r = 0; r < 4; ++r)
                    pk[r] = bf16_bits(acc[mt][nt][r] + bvv);
                const int bh2 = (m >> 12) * kH + (n >> 6);
                short* dst = (short*)Vtw
                    + ((size_t)bh2 * kHD + (size_t)(n & (kHD - 1))) * kS
                    + (size_t)(m & (kS - 1));
                *(short4v*)dst = pk;
            } else {
                __hip_bfloat16* dst = sel == 0 ? Qw : Kw;
                const float scale = sel == 0 ? 0.18033688f : 1.0f;  // 0.125*log2e
                #pragma unroll
                for (int r = 0; r < 4; ++r) {
                    const int m = m0 + wm * 64 + mt * 16 + quad * 4 + r;
                    const float v = (acc[mt][nt][r] + bvv) * scale;
                    const size_t addr = (((size_t)(m >> 12) * kH + (n >> 6)) * kS
                                         + (size_t)(m & (kS - 1))) * kHD
                                        + (size_t)(n & (kHD - 1));
                    dst[addr] = __float2bfloat16(v);
                }
            }
        }
    }
}

// Output projection: out(fp32) = O(bf16) @ Wo.T + bo. 128x128 tiles.
__global__ __launch_bounds__(256, 4) void gemm_out(
    const __hip_bfloat16* __restrict__ X, const __hip_bfloat16* __restrict__ W,
    const float* __restrict__ bias, float* __restrict__ out)
{
    __shared__ short As[128 * 64];
    __shared__ short Bs[128 * 64];

    const int lane = threadIdx.x & 63, wave = threadIdx.x >> 6;
    const int quad = lane >> 4, l16 = lane & 15;
    const int m0 = blockIdx.x * 128, n0 = blockIdx.y * 128;
    const int wm = wave & 1, wn = wave >> 1;

    const short* Xg = (const short*)X + (size_t)m0 * kD;
    const short* Wg = (const short*)W + (size_t)n0 * kD;

    f32x4 acc[4][4];
    #pragma unroll
    for (int mt = 0; mt < 4; ++mt)
        #pragma unroll
        for (int nt = 0; nt < 4; ++nt) acc[mt][nt] = f32x4{0.f, 0.f, 0.f, 0.f};

    const int srow = lane >> 3;
    const int gch  = (lane & 7) ^ srow;

    for (int k0 = 0; k0 < kD; k0 += 64) {
        __syncthreads();
        #pragma unroll
        for (int i = 0; i < 4; ++i) {
            const int rowbase = wave * 32 + i * 8;
            const int row = rowbase + srow;
            GLDS16(Xg + (size_t)row * kD + k0 + gch * 8, &As[rowbase * 64]);
            GLDS16(Wg + (size_t)row * kD + k0 + gch * 8, &Bs[rowbase * 64]);
        }
        __syncthreads();

        #pragma unroll
        for (int c = 0; c < 2; ++c) {
            short8 af[4], bf[4];
            const int rx = l16 & 7;
            #pragma unroll
            for (int mt = 0; mt < 4; ++mt)
                af[mt] = *(const short8*)&As[(wm * 64 + mt * 16 + l16) * 64
                                             + (((c * 4 + quad) ^ rx) * 8)];
            #pragma unroll
            for (int nt = 0; nt < 4; ++nt)
                bf[nt] = *(const short8*)&Bs[(wn * 64 + nt * 16 + l16) * 64
                                             + (((c * 4 + quad) ^ rx) * 8)];
            #pragma unroll
            for (int mt = 0; mt < 4; ++mt)
                #pragma unroll
                for (int nt = 0; nt < 4; ++nt)
                    acc[mt][nt] = MFMA16(af[mt], bf[nt], acc[mt][nt]);
        }
    }

    #pragma unroll
    for (int nt = 0; nt < 4; ++nt) {
        const int n = n0 + wn * 64 + nt * 16 + l16;
        const float bv = bias[n];
        #pragma unroll
        for (int mt = 0; mt < 4; ++mt)
            #pragma unroll
            for (int r = 0; r < 4; ++r) {
                const int m = m0 + wm * 64 + mt * 16 + quad * 4 + r;
                out[(size_t)m * kD + n] = acc[mt][nt][r] + bv;
            }
    }
}

// Flash attention v6 (R5 exact — best verified: 178us, MfmaUtil 37, 0 conflicts).
// Qw pre-scaled by 0.125*log2e; Kw [BH][S][64]; Vt [BH][64][S].
// Permuted-K fragment staging (zero conflicts, zero runtime transpose), T=4
// q-tiles/wave (64 q-rows), KVBLK=64, one barrier per tile, lsum on MFMA.
__global__ __launch_bounds__(256, 2) void flash2(
    const __hip_bfloat16* __restrict__ Qw, const __hip_bfloat16* __restrict__ Kw,
    const __hip_bfloat16* __restrict__ Vt, __hip_bfloat16* __restrict__ O)
{
    __shared__ short Ks[2][8 * 512];   // 8 fragment blocks of 1KB per buffer
    __shared__ short Vs[2][8 * 512];

    const int lane = threadIdx.x & 63, wave = threadIdx.x >> 6;
    const int quad = lane >> 4, l16 = lane & 15;

    // XCD-aware swizzle: 512 blocks, 8 XCDs -> contiguous 64-block chunks
    // (= 4 bh per XCD -> K/V working set 4MB = one L2).
    const int flat = blockIdx.y * 16 + blockIdx.x;
    const int swz  = (flat & 7) * 64 + (flat >> 3);
    const int bh = swz >> 4, b = bh >> 4, h = bh & 15;
    const int qbase = (swz & 15) * 256 + wave * 64;

    const short* Qg = (const short*)Qw + ((size_t)bh * kS + qbase) * kHD;
    short8 qf[4][2];
    #pragma unroll
    for (int t = 0; t < 4; ++t)
        #pragma unroll
        for (int c = 0; c < 2; ++c)
            qf[t][c] = *(const short8*)(Qg + (t * 16 + l16) * kHD + c * 32 + quad * 8);

    const short* Kg = (const short*)Kw + (size_t)bh * kS * kHD;
    const short* Vg = (const short*)Vt + (size_t)bh * kHD * kS;

    const short ONE = 0x3F80;
    const short8 onesf = {ONE, ONE, ONE, ONE, ONE, ONE, ONE, ONE};

    f32x4 o[4][4], lsumv[4];
    #pragma unroll
    for (int t = 0; t < 4; ++t) {
        lsumv[t] = f32x4{0.f, 0.f, 0.f, 0.f};
        #pragma unroll
        for (int dt = 0; dt < 4; ++dt) o[t][dt] = f32x4{0.f, 0.f, 0.f, 0.f};
    }

    // --- staging pointers (running; advanced by one 64-k tile per iter) ---
    // K: wave w stages fragments f=w*2+i == (c=w>>1)*4 + (m=w&1)*2 + (dhalf=i).
    //    lane (l16,quad) sources K[row = c*32 + 8*(l16>>2)+4m+(l16&3)]
    //                             [d = dhalf*32 + quad*8 .. +7]  (permuted rows)
    const int kc = wave >> 1, km = wave & 1;
    const int krow = kc * 32 + 8 * (l16 >> 2) + 4 * km + (l16 & 3);
    const short* ka0 = Kg + (size_t)krow * kHD + quad * 8;        // dhalf 0
    const short* ka1 = ka0 + 32;                                  // dhalf 1
    // V: wave w stages fragments f=w*2+i == (c=w>>1)*4 + (dt=(w&1)*2+i).
    //    lane (l16,quad) sources Vt[d = dt*16 + l16][s = c*32 + quad*8 ..]
    const int vdt = (wave & 1) * 2, vc32 = (wave >> 1) * 32;
    const short* va0 = Vg + (size_t)((vdt + 0) * 16 + l16) * kS + vc32 + quad * 8;
    const short* va1 = Vg + (size_t)((vdt + 1) * 16 + l16) * kS + vc32 + quad * 8;

    // prefetch tile 0 (fragment order)
    GLDS16(ka0, &Ks[0][(wave * 2 + 0) * 512]);
    GLDS16(ka1, &Ks[0][(wave * 2 + 1) * 512]);
    GLDS16(va0, &Vs[0][(wave * 2 + 0) * 512]);
    GLDS16(va1, &Vs[0][(wave * 2 + 1) * 512]);
    ka0 += 64 * kHD; ka1 += 64 * kHD; va0 += 64; va1 += 64;

    for (int k0 = 0; k0 < kS; k0 += 64) {
        const int cur = (k0 >> 6) & 1;
        __syncthreads();   // drains in-flight GLDS + guards buffer reuse
        if (k0 + 64 < kS) {
            const int nxt = cur ^ 1;
            GLDS16(ka0, &Ks[nxt][(wave * 2 + 0) * 512]);
            GLDS16(ka1, &Ks[nxt][(wave * 2 + 1) * 512]);
            GLDS16(va0, &Vs[nxt][(wave * 2 + 0) * 512]);
            GLDS16(va1, &Vs[nxt][(wave * 2 + 1) * 512]);
            ka0 += 64 * kHD; ka1 += 64 * kHD; va0 += 64; va1 += 64;
        }

        // per 32-wide k-half: QK^T (+exp, pack directly into PV-A order) -> PV.
        #pragma unroll
        for (int c = 0; c < 2; ++c) {
            // V fragments early: LDS latency hides under the QK MFMAs.
            short8 vb[4];
            #pragma unroll
            for (int dt = 0; dt < 4; ++dt)
                vb[dt] = *(const short8*)&Vs[cur][(c * 4 + dt) * 512 + lane * 8];

            unsigned int P[4][4];
            #pragma unroll
            for (int m = 0; m < 2; ++m) {
                const int fb = c * 4 + m * 2;
                short8 a0 = *(const short8*)&Ks[cur][(fb + 0) * 512 + lane * 8];
                short8 a1 = *(const short8*)&Ks[cur][(fb + 1) * 512 + lane * 8];
                #pragma unroll
                for (int t = 0; t < 4; ++t) {
                    f32x4 z = {0.f, 0.f, 0.f, 0.f};
                    f32x4 s = MFMA16(a0, qf[t][0], z);
                    s = MFMA16(a1, qf[t][1], s);
                    // lane ends with khalf = 8*quad + 4m + r  (PV-A order)
                    P[t][m * 2 + 0] = pk_bf16(__builtin_amdgcn_exp2f(s[0]),
                                              __builtin_amdgcn_exp2f(s[1]));
                    P[t][m * 2 + 1] = pk_bf16(__builtin_amdgcn_exp2f(s[2]),
                                              __builtin_amdgcn_exp2f(s[3]));
                }
            }

            short8 pa[4];
            #pragma unroll
            for (int t = 0; t < 4; ++t) {
                uint4v u = {P[t][0], P[t][1], P[t][2], P[t][3]};
                pa[t] = __builtin_bit_cast(short8, u);
            }

            __builtin_amdgcn_s_setprio(1);
            #pragma unroll
            for (int t = 0; t < 4; ++t)
                lsumv[t] = MFMA16(pa[t], onesf, lsumv[t]);
            #pragma unroll
            for (int dt = 0; dt < 4; ++dt)
                #pragma unroll
                for (int t = 0; t < 4; ++t)
                    o[t][dt] = MFMA16(pa[t], vb[dt], o[t][dt]);
            __builtin_amdgcn_s_setprio(0);
        }
    }

    // ---- epilogue: /l (C-layout rows match o), store [B,S,D] bf16 ----
    #pragma unroll
    for (int t = 0; t < 4; ++t)
        #pragma unroll
        for (int r = 0; r < 4; ++r) {
            const float inv = 1.0f / lsumv[t][r];
            const int sq = qbase + t * 16 + quad * 4 + r;
            #pragma unroll
            for (int dt = 0; dt < 4; ++dt)
                O[((size_t)b * kS + sq) * kD + h * kHD + dt * 16 + l16] =
                    __float2bfloat16(o[t][dt][r] * inv);
        }
}

// ===========================================================================
// FALLBACK PATH (round-8 structure) — unchanged
// ===========================================================================
template <bool KV8, bool WB16>
__global__ __launch_bounds__(256) void gemm_kv(
    const float* __restrict__ X, const void* __restrict__ W,
    const float* __restrict__ bias, void* __restrict__ outv)
{
    const int lane = threadIdx.x & 63;
    const int wave = threadIdx.x >> 6;
    const int quad = lane >> 4;
    const int l16  = lane & 15;
    const int m0 = blockIdx.x * 16;
    const int n0 = blockIdx.y * 256 + wave * 64;

    const float* xr = X + (size_t)(m0 + l16) * kD;
    const float* wf = (const float*)W + (size_t)(n0 + l16) * kD;
    const short* wb = (const short*)W + (size_t)(n0 + l16) * kD;

    f32x4 acc[4] = {{0.f,0.f,0.f,0.f},{0.f,0.f,0.f,0.f},
                    {0.f,0.f,0.f,0.f},{0.f,0.f,0.f,0.f}};

    for (int k8 = quad; k8 < kD / 8; k8 += 4) {
        short8 a = cvt8(xr + k8 * 8);
        #pragma unroll
        for (int nt = 0; nt < 4; ++nt) {
            short8 w = WB16 ? *(const short8*)(wb + nt * 16 * kD + k8 * 8)
                            : cvt8(wf + nt * 16 * kD + k8 * 8);
            acc[nt] = MFMA16(a, w, acc[nt]);
        }
    }

    #pragma unroll
    for (int nt = 0; nt < 4; ++nt) {
        const int n = n0 + nt * 16 + l16;
        const float bv = bias[n];
        #pragma unroll
        for (int r = 0; r < 4; ++r) {
            const int m = m0 + quad * 4 + r;
            const float v = acc[nt][r] + bv;
            const size_t addr = (((size_t)(m >> 12) * kH + (n >> 6)) * kS
                                 + (size_t)(m & (kS - 1))) * kHD + (size_t)(n & (kHD - 1));
            if (KV8) ((unsigned char*)outv)[addr] = f32_to_e4m3(v);
            else     ((__hip_bfloat16*)outv)[addr] = __float2bfloat16(v);
        }
    }
}

template <bool KV8, bool WB16>
__global__ __launch_bounds__(256) void flash_fusedq(
    const float* __restrict__ x,  const void* __restrict__ Wq,
    const float* __restrict__ bq, const void* __restrict__ Kw,
    const void* __restrict__ Vw,  __hip_bfloat16* __restrict__ O)
{
    __shared__ short pool[9216];
    __shared__ short Ps[4][32][72];

    const int lane = threadIdx.x & 63;
    const int wave = threadIdx.x >> 6;
    const int quad = lane >> 4;
    const int l16  = lane & 15;
    const int bh   = blockIdx.y;
    const int b    = bh >> 4, h = bh & 15;
    const int qbase = blockIdx.x * 128 + wave * 32;

    {
        const float* xr0 = x + (size_t)(b * kS + qbase + l16) * kD;
        const float* xr1 = xr0 + (size_t)16 * kD;
        const float* wqf = (const float*)Wq + (size_t)(h * kHD + l16) * kD;
        const short* wqb = (const short*)Wq + (size_t)(h * kHD + l16) * kD;
        f32x4 qa[2][4];
        #pragma unroll
        for (int t = 0; t < 2; ++t)
            #pragma unroll
            for (int nt = 0; nt < 4; ++nt) qa[t][nt] = f32x4{0.f,0.f,0.f,0.f};

        for (int k8 = quad; k8 < kD / 8; k8 += 4) {
            short8 a0 = cvt8(xr0 + k8 * 8);
            short8 a1 = cvt8(xr1 + k8 * 8);
            #pragma unroll
            for (int nt = 0; nt < 4; ++nt) {
                short8 w = WB16 ? *(const short8*)(wqb + nt * 16 * kD + k8 * 8)
                                : cvt8(wqf + nt * 16 * kD + k8 * 8);
                qa[0][nt] = MFMA16(a0, w, qa[0][nt]);
                qa[1][nt] = MFMA16(a1, w, qa[1][nt]);
            }
        }
        #pragma unroll
        for (int t = 0; t < 2; ++t)
            #pragma unroll
            for (int nt = 0; nt < 4; ++nt) {
                const float bv = bq[h * kHD + nt * 16 + l16];
                #pragma unroll
                for (int r = 0; r < 4; ++r)
                    pool[wave * 2304 + (t * 16 + quad * 4 + r) * 72 + nt * 16 + l16] =
                        bf16_bits((qa[t][nt][r] + bv) * 0.125f);
            }
    }
    short8 qf[2][2];
    #pragma unroll
    for (int t = 0; t < 2; ++t)
        #pragma unroll
        for (int c = 0; c < 2; ++c)
            qf[t][c] = *(const short8*)&pool[wave * 2304 + (t * 16 + l16) * 72 + c * 32 + quad * 8];

    f32x4 o[2][4];
    float mrow[2][4], lrow[2][4];
    #pragma unroll
    for (int t = 0; t < 2; ++t)
        #pragma unroll
        for (int dt = 0; dt < 4; ++dt) o[t][dt] = f32x4{0.f,0.f,0.f,0.f};
    #pragma unroll
    for (int t = 0; t < 2; ++t)
        #pragma unroll
        for (int r = 0; r < 4; ++r) { mrow[t][r] = -INFINITY; lrow[t][r] = 0.f; }

    const __hip_bfloat16* Kb16 = (const __hip_bfloat16*)Kw + (size_t)bh * kS * kHD;
    const __hip_bfloat16* Vb16 = (const __hip_bfloat16*)Vw + (size_t)bh * kS * kHD;
    const unsigned char*  K8   = (const unsigned char*)Kw + (size_t)bh * kS * kHD;
    const unsigned char*  V8   = (const unsigned char*)Vw + (size_t)bh * kS * kHD;

    for (int k0 = 0; k0 < kS; k0 += 64) {
        __syncthreads();
        #pragma unroll
        for (int i = 0; i < 2; ++i) {
            const int lin = threadIdx.x + i * 256;
            const int kr = lin >> 3, c8 = lin & 7;
            short8 kv, vv;
            if (KV8) {
                uint2 kbits = *(const uint2*)(K8 + (size_t)(k0 + kr) * kHD + c8 * 8);
                uint2 vbits = *(const uint2*)(V8 + (size_t)(k0 + kr) * kHD + c8 * 8);
                #pragma unroll
                for (int j = 0; j < 4; ++j) {
                    kv[j]     = bf16_bits(e4m3_to_f32((kbits.x >> (8 * j)) & 255u));
                    kv[4 + j] = bf16_bits(e4m3_to_f32((kbits.y >> (8 * j)) & 255u));
                    vv[j]     = bf16_bits(e4m3_to_f32((vbits.x >> (8 * j)) & 255u));
                    vv[4 + j] = bf16_bits(e4m3_to_f32((vbits.y >> (8 * j)) & 255u));
                }
            } else {
                kv = *(const short8*)(Kb16 + (size_t)(k0 + kr) * kHD + c8 * 8);
                vv = *(const short8*)(Vb16 + (size_t)(k0 + kr) * kHD + c8 * 8);
            }
            *(short8*)&pool[kr * 72 + c8 * 8] = kv;
            #pragma unroll
            for (int j = 0; j < 8; ++j)
                pool[4608 + (c8 * 8 + j) * 72 + (((kr >> 3) ^ c8) << 3) + (kr & 7)] = vv[j];
        }
        __syncthreads();

        f32x4 sc[2][4];
        #pragma unroll
        for (int kt = 0; kt < 4; ++kt) {
            short8 b0 = *(const short8*)&pool[(kt * 16 + l16) * 72 + quad * 8];
            short8 b1 = *(const short8*)&pool[(kt * 16 + l16) * 72 + 32 + quad * 8];
            f32x4 z = {0.f, 0.f, 0.f, 0.f};
            f32x4 s0 = MFMA16(qf[0][0], b0, z); s0 = MFMA16(qf[0][1], b1, s0);
            f32x4 s1 = MFMA16(qf[1][0], b0, z); s1 = MFMA16(qf[1][1], b1, s1);
            sc[0][kt] = s0; sc[1][kt] = s1;
        }

        #pragma unroll
        for (int t = 0; t < 2; ++t)
            #pragma unroll
            for (int r = 0; r < 4; ++r) {
                float s0 = sc[t][0][r], s1 = sc[t][1][r];
                float s2 = sc[t][2][r], s3 = sc[t][3][r];
                float mx = fmaxf(fmaxf(s0, s1), fmaxf(s2, s3));
                #pragma unroll
                for (int off = 1; off < 16; off <<= 1)
                    mx = fmaxf(mx, __shfl_xor(mx, off, 64));
                const float mnew  = fmaxf(mrow[t][r], mx);
                const float alpha = __builtin_amdgcn_exp2f((mrow[t][r] - mnew) * 1.44269504f);
                mrow[t][r] = mnew;
                const float p0 = __builtin_amdgcn_exp2f((s0 - mnew) * 1.44269504f);
                const float p1 = __builtin_amdgcn_exp2f((s1 - mnew) * 1.44269504f);
                const float p2 = __builtin_amdgcn_exp2f((s2 - mnew) * 1.44269504f);
                const float p3 = __builtin_amdgcn_exp2f((s3 - mnew) * 1.44269504f);
                float ps = (p0 + p1) + (p2 + p3);
                #pragma unroll
                for (int off = 1; off < 16; off <<= 1)
                    ps += __shfl_xor(ps, off, 64);
                lrow[t][r] = lrow[t][r] * alpha + ps;
                o[t][0][r] *= alpha; o[t][1][r] *= alpha;
                o[t][2][r] *= alpha; o[t][3][r] *= alpha;
                const int row = t * 16 + quad * 4 + r;
                Ps[wave][row][l16]      = bf16_bits(p0);
                Ps[wave][row][16 + l16] = bf16_bits(p1);
                Ps[wave][row][32 + l16] = bf16_bits(p2);
                Ps[wave][row][48 + l16] = bf16_bits(p3);
            }

        short8 pa[2][2];
        #pragma unroll
        for (int t = 0; t < 2; ++t)
            #pragma unroll
            for (int c = 0; c < 2; ++c)
                pa[t][c] = *(const short8*)&Ps[wave][t * 16 + l16][c * 32 + quad * 8];
        #pragma unroll
        for (int c = 0; c < 2; ++c)
            #pragma unroll
            for (int dt = 0; dt < 4; ++dt) {
                const int d = dt * 16 + l16;
                short8 vb = *(const short8*)&pool[4608 + d * 72 + ((((c * 4 + quad)) ^ (d >> 3)) << 3)];
                o[0][dt] = MFMA16(pa[0][c], vb, o[0][dt]);
                o[1][dt] = MFMA16(pa[1][c], vb, o[1][dt]);
            }
    }

    #pragma unroll
    for (int t = 0; t < 2; ++t)
        #pragma unroll
        for (int r = 0; r < 4; ++r) {
            const float inv = 1.0f / lrow[t][r];
            const int sq = qbase + t * 16 + quad * 4 + r;
            #pragma unroll
            for (int dt = 0; dt < 4; ++dt)
                O[((size_t)b * kS + sq) * kD + h * kHD + dt * 16 + l16] =
                    __float2bfloat16(o[t][dt][r] * inv);
        }
}

template <bool WB16>
__global__ __launch_bounds__(256) void proj_out(
    const __hip_bfloat16* __restrict__ Xb, const void* __restrict__ W,
    const float* __restrict__ bias, float* __restrict__ out)
{
    const int lane = threadIdx.x & 63;
    const int wave = threadIdx.x >> 6;
    const int quad = lane >> 4;
    const int l16  = lane & 15;
    const int m0 = blockIdx.x * 16;
    const int n0 = blockIdx.y * 256 + wave * 64;

    const short8* xr = (const short8*)((const short*)Xb + (size_t)(m0 + l16) * kD);
    const float*  wf = (const float*)W + (size_t)(n0 + l16) * kD;
    const short*  wb = (const short*)W + (size_t)(n0 + l16) * kD;

    f32x4 acc[4] = {{0.f,0.f,0.f,0.f},{0.f,0.f,0.f,0.f},
                    {0.f,0.f,0.f,0.f},{0.f,0.f,0.f,0.f}};

    for (int k8 = quad; k8 < kD / 8; k8 += 4) {
        short8 a = xr[k8];
        #pragma unroll
        for (int nt = 0; nt < 4; ++nt) {
            short8 w = WB16 ? *(const short8*)(wb + nt * 16 * kD + k8 * 8)
                            : cvt8(wf + nt * 16 * kD + k8 * 8);
            acc[nt] = MFMA16(a, w, acc[nt]);
        }
    }

    #pragma unroll
    for (int nt = 0; nt < 4; ++nt) {
        const int n = n0 + nt * 16 + l16;
        const float bv = bias[n];
        #pragma unroll
        for (int r = 0; r < 4; ++r) {
            const int m = m0 + quad * 4 + r;
            out[(size_t)m * kD + n] = acc[nt][r] + bv;
        }
    }
}

extern "C" void kernel_launch(void* const* d_in, const int* in_sizes, int n_in,
                              void* d_out, int out_size, void* d_ws, size_t ws_size,
                              hipStream_t stream)
{
    const float* x = nullptr;
    const float* Wm[4] = {nullptr, nullptr, nullptr, nullptr};
    const float* bm[4] = {nullptr, nullptr, nullptr, nullptr};
    int wi = 0, bi = 0;
    for (int i = 0; i < n_in; ++i) {
        const int s = in_sizes[i];
        if      (s == 2 * kS * kD)         x = (const float*)d_in[i];
        else if (s == kD * kD && wi < 4)   Wm[wi++] = (const float*)d_in[i];
        else if (s == kD      && bi < 4)   bm[bi++] = (const float*)d_in[i];
    }
    const float *Wq = Wm[0], *Wk = Wm[1], *Wv = Wm[2], *Wo = Wm[3];
    const float *bq = bm[0], *bk = bm[1], *bv = bm[2], *bo = bm[3];
    float* out = (float*)d_out;   // output is fp32

    const size_t elems = (size_t)2 * kS * kD;   // 8,388,608
    const size_t wel   = (size_t)kD * kD;       // 1,048,576
    const size_t MB = 1024 * 1024;
    dim3 bb(256);

    if (ws_size >= 88 * MB) {
        // xb(16) | Qw(16) | Kw(16) | Vt(16) | Ow(16) | 4x Wb(8) = 88MB
        __hip_bfloat16* xb  = (__hip_bfloat16*)d_ws;
        __hip_bfloat16* Qw  = xb + elems;
        __hip_bfloat16* Kw  = Qw + elems;
        __hip_bfloat16* Vtw = Kw + elems;
        __hip_bfloat16* Ow  = Vtw + elems;
        __hip_bfloat16* Wqb = Ow + elems;     // W q/k/v/o contiguous
        __hip_bfloat16* Wob = Wqb + 3 * wel;

        cvt_all<<<dim3(12288), bb, 0, stream>>>(x, Wq, Wk, Wv, Wo, xb, Wqb);

        gemm_qkv<<<dim3(64, 24), bb, 0, stream>>>(xb, Wqb, bq, bk, bv, Qw, Kw, Vtw);
        flash2<<<dim3(16, 32), bb, 0, stream>>>(Qw, Kw, Vtw, Ow);
        gemm_out<<<dim3(64, 8), bb, 0, stream>>>(Ow, Wob, bo, out);
        return;
    }

    dim3 gg(512, 4), gf(kS / 128, 2 * kH);
    if (ws_size >= 56 * MB) {
        __hip_bfloat16* Kw  = (__hip_bfloat16*)d_ws;
        __hip_bfloat16* Vw  = Kw + elems;
        __hip_bfloat16* Ow  = Vw + elems;
        __hip_bfloat16* Wqb = Ow + elems;
        __hip_bfloat16* Wkb = Wqb + wel;
        __hip_bfloat16* Wvb = Wkb + wel;
        __hip_bfloat16* Wob = Wvb + wel;
        cvt_w4<<<dim3(4096), bb, 0, stream>>>(Wq, Wk, Wv, Wo, Wqb);
        gemm_kv<false, true><<<gg, bb, 0, stream>>>(x, Wkb, bk, Kw);
        gemm_kv<false, true><<<gg, bb, 0, stream>>>(x, Wvb, bv, Vw);
        flash_fusedq<false, true><<<gf, bb, 0, stream>>>(x, Wqb, bq, Kw, Vw, Ow);
        proj_out<true><<<gg, bb, 0, stream>>>(Ow, Wob, bo, out);
    } else if (ws_size >= 48 * MB) {
        __hip_bfloat16* Kw = (__hip_bfloat16*)d_ws;
        __hip_bfloat16* Vw = Kw + elems;
        __hip_bfloat16* Ow = Vw + elems;
        gemm_kv<false, false><<<gg, bb, 0, stream>>>(x, Wk, bk, Kw);
        gemm_kv<false, false><<<gg, bb, 0, stream>>>(x, Wv, bv, Vw);
        flash_fusedq<false, false><<<gf, bb, 0, stream>>>(x, Wq, bq, Kw, Vw, Ow);
        proj_out<false><<<gg, bb, 0, stream>>>(Ow, Wo, bo, out);
    } else {
        unsigned char* Kw = (unsigned char*)d_ws;
        unsigned char* Vw = Kw + elems;
        __hip_bfloat16* Ow = (__hip_bfloat16*)(Vw + elems);
        gemm_kv<true, false><<<gg, bb, 0, stream>>>(x, Wk, bk, Kw);
        gemm_kv<true, false><<<gg, bb, 0, stream>>>(x, Wv, bv, Vw);
        flash_fusedq<true, false><<<gf, bb, 0, stream>>>(x, Wq, bq, Kw, Vw, Ow);
        proj_out<false><<<gg, bb, 0, stream>>>(Ow, Wo, bo, out);
    }
}